// Round 22
// baseline (453.015 us; speedup 1.0000x reference)
//
#include <hip/hip_runtime.h>
#include <hip/hip_bf16.h>

#define TPB 256

typedef __attribute__((ext_vector_type(8))) short bf16x8;
typedef __attribute__((ext_vector_type(4))) float f32x4;

static __device__ __forceinline__ unsigned short f2bf(float f) {
  union { float f; unsigned int u; } x; x.f = f;
  unsigned int r = x.u + 0x7FFF + ((x.u >> 16) & 1);   // RNE
  return (unsigned short)(r >> 16);
}
static __device__ __forceinline__ float bf2f(unsigned short h) {
  union { unsigned int u; float f; } x; x.u = ((unsigned int)h) << 16;
  return x.f;
}

#define MFMA16(a, b, c) __builtin_amdgcn_mfma_f32_16x16x32_bf16(a, b, c, 0, 0, 0)

// ---------------------------------------------------------------------------
// Fused fold-stage kernel (stages 1-3) + wp slices + out-init.
// ---------------------------------------------------------------------------
__global__ __launch_bounds__(TPB) void fold_wp_fused_k(
    const float* __restrict__ A, const float* __restrict__ lastrow,
    const float* __restrict__ W, const float* __restrict__ bias,
    float* __restrict__ C, int K, int Nc, int gemmBlocks,
    const float* __restrict__ Wp1, const float* __restrict__ Wp2,
    float* __restrict__ wfold, int wpStart, int wpCount,
    const float* __restrict__ bp1, const float* __restrict__ bp2,
    float* __restrict__ out)
{
  __shared__ float As[64][68];
  __shared__ float Ws[64][68];
  __shared__ float red[4];
  int bid = blockIdx.x, tid = threadIdx.x;

  if (bid >= gemmBlocks) {
    int u = bid - gemmBlocks;
    int wv = tid >> 6, lane = tid & 63;
    if (u >= wpCount) {
      float s = 0.f;
      for (int i = tid; i < 1536; i += TPB) s += bp1[i] * Wp2[i];
#pragma unroll
      for (int off = 32; off >= 1; off >>= 1) s += __shfl_xor(s, off, 64);
      if (lane == 0) red[wv] = s;
      __syncthreads();
      if (tid < 96) out[tid] = red[0] + red[1] + red[2] + red[3] + bp2[0];
      return;
    }
    float* w2 = &As[0][0];
    for (int i = tid; i < 1536; i += TPB) w2[i] = Wp2[i];
    __syncthreads();
    int m = (wpStart + u) * 4 + wv;
    const float* row = Wp1 + (size_t)m * 1536;
    float s = 0.f;
#pragma unroll
    for (int k = 0; k < 6; ++k) {
      float4 a  = *(const float4*)(row + k * 256 + lane * 4);
      float4 ww = *(const float4*)&w2[k * 256 + lane * 4];
      s += a.x * ww.x + a.y * ww.y + a.z * ww.z + a.w * ww.w;
    }
#pragma unroll
    for (int off = 32; off >= 1; off >>= 1) s += __shfl_xor(s, off, 64);
    if (lane == 0) wfold[m] = s;
    return;
  }

  int col0 = bid * 64;
  int ty = tid >> 4, tx = tid & 15;
  float acc[4][4] = {};
  for (int k0 = 0; k0 < K; k0 += 64) {
#pragma unroll
    for (int i = 0; i < 16; ++i) {
      int idx = tid + i * TPB;
      int r = idx >> 6, kk = idx & 63;
      int gk = k0 + kk;
      float v = 0.f;
      if (gk < K) {
        if (r < 50) v = A[(size_t)r * K + gk];
        else if (r == 50) v = lastrow[gk];
      }
      As[kk][r] = v;
    }
#pragma unroll
    for (int i = 0; i < 16; ++i) {
      int idx = tid + i * TPB;
      int kk = idx >> 6, cc = idx & 63;
      int gk = k0 + kk, gc = col0 + cc;
      float v = 0.f;
      if (gk < K && gc < Nc) v = W[(size_t)gk * Nc + gc];
      Ws[kk][cc] = v;
    }
    __syncthreads();
#pragma unroll 8
    for (int kk = 0; kk < 64; ++kk) {
      float4 a4 = *(const float4*)&As[kk][ty * 4];
      float4 b4 = *(const float4*)&Ws[kk][tx * 4];
      float av[4] = {a4.x, a4.y, a4.z, a4.w};
      float bv[4] = {b4.x, b4.y, b4.z, b4.w};
#pragma unroll
      for (int i = 0; i < 4; ++i)
#pragma unroll
        for (int j = 0; j < 4; ++j)
          acc[i][j] = fmaf(av[i], bv[j], acc[i][j]);
    }
    __syncthreads();
  }
#pragma unroll
  for (int i = 0; i < 4; ++i) {
    int gr = ty * 4 + i;
    if (gr >= 51) continue;
#pragma unroll
    for (int j = 0; j < 4; ++j) {
      int gc = col0 + tx * 4 + j;
      if (gc >= Nc) continue;
      float v = acc[i][j];
      if (gr == 50) v += bias[gc];
      C[(size_t)gr * Nc + gc] = v;
    }
  }
}

// ---------------------------------------------------------------------------
// Fused stage4: gemm -> WfTh/WfTl/bfv; x-prep -> xh/xl/xT; wp slice.
// ---------------------------------------------------------------------------
__global__ __launch_bounds__(TPB) void fold4_fused_k(
    const float* __restrict__ aug3,
    const float* __restrict__ Wruv,
    const float* __restrict__ bruv,
    unsigned short* __restrict__ WfTh, unsigned short* __restrict__ WfTl,
    float* __restrict__ bfv,
    const float* __restrict__ x,
    unsigned short* __restrict__ xh, unsigned short* __restrict__ xl,
    unsigned short* __restrict__ xT,
    const float* __restrict__ Wp1, const float* __restrict__ Wp2,
    float* __restrict__ wfold, int wpStart, int wpCount)
{
  __shared__ float As[64][68];
  __shared__ float Ws[64][68];
  int bid = blockIdx.x, tid = threadIdx.x;

  if (bid >= 157) {
    int u = bid - 157;
    if (u >= wpCount) return;
    int wv = tid >> 6, lane = tid & 63;
    float* w2 = &As[0][0];
    for (int i = tid; i < 1536; i += TPB) w2[i] = Wp2[i];
    __syncthreads();
    int m = (wpStart + u) * 4 + wv;
    const float* row = Wp1 + (size_t)m * 1536;
    float s = 0.f;
#pragma unroll
    for (int k = 0; k < 6; ++k) {
      float4 a  = *(const float4*)(row + k * 256 + lane * 4);
      float4 ww = *(const float4*)&w2[k * 256 + lane * 4];
      s += a.x * ww.x + a.y * ww.y + a.z * ww.z + a.w * ww.w;
    }
#pragma unroll
    for (int off = 32; off >= 1; off >>= 1) s += __shfl_xor(s, off, 64);
    if (lane == 0) wfold[m] = s;
    return;
  }

  if (bid >= 36) {
    int row0 = (bid - 36) * 64;
#pragma unroll
    for (int i = 0; i < 16; ++i) {
      int idx = tid + i * TPB;
      int row = row0 + (idx >> 6), cc = idx & 63;
      if (row >= 7688) continue;
      float v = 0.f;
      if (cc < 50) v = x[(size_t)row * 50 + cc];
      else if (cc == 50) v = 1.0f;
      unsigned short hi = f2bf(v);
      xh[(size_t)row * 64 + cc] = hi;
      xl[(size_t)row * 64 + cc] = f2bf(v - bf2f(hi));
      int bb = row / 961;
      int nl = row - bb * 961;
      xT[((size_t)bb * 64 + cc) * 968 + nl] = hi;
    }
    return;
  }

  const int K = 768, Nc = 2304;
  const float* lastrow = aug3 + (size_t)50 * 768;
  int col0 = bid * 64;
  int ty = tid >> 4, tx = tid & 15;
  float acc[4][4] = {};
  for (int k0 = 0; k0 < K; k0 += 64) {
#pragma unroll
    for (int i = 0; i < 16; ++i) {
      int idx = tid + i * TPB;
      int r = idx >> 6, kk = idx & 63;
      int gk = k0 + kk;
      float v = 0.f;
      if (r < 50) v = aug3[(size_t)r * K + gk];
      else if (r == 50) v = lastrow[gk];
      As[kk][r] = v;
    }
#pragma unroll
    for (int i = 0; i < 16; ++i) {
      int idx = tid + i * TPB;
      int kk = idx >> 6, cc = idx & 63;
      Ws[kk][cc] = Wruv[(size_t)(k0 + kk) * Nc + col0 + cc];
    }
    __syncthreads();
#pragma unroll 8
    for (int kk = 0; kk < 64; ++kk) {
      float4 a4 = *(const float4*)&As[kk][ty * 4];
      float4 b4 = *(const float4*)&Ws[kk][tx * 4];
      float av[4] = {a4.x, a4.y, a4.z, a4.w};
      float bv[4] = {b4.x, b4.y, b4.z, b4.w};
#pragma unroll
      for (int i = 0; i < 4; ++i)
#pragma unroll
        for (int j = 0; j < 4; ++j)
          acc[i][j] = fmaf(av[i], bv[j], acc[i][j]);
    }
    __syncthreads();
  }
#pragma unroll
  for (int i = 0; i < 4; ++i) {
    int gr = ty * 4 + i;
    if (gr >= 51) continue;
#pragma unroll
    for (int j = 0; j < 4; ++j) {
      int gc = col0 + tx * 4 + j;
      float v = acc[i][j];
      if (gr == 50) {
        bfv[gc] = v + bruv[gc];
      } else {
        unsigned short hi = f2bf(v);
        size_t el = (size_t)gc * 64 + gr;
        WfTh[el] = hi;
        WfTl[el] = f2bf(v - bf2f(hi));
      }
    }
  }
}

// ---------------------------------------------------------------------------
// prepM_k: M~T only (12 blocks). LDS-staged fp32 (r18-proven path).
// ---------------------------------------------------------------------------
__global__ __launch_bounds__(TPB) void prepM_k(
    const unsigned short* __restrict__ WfTh,
    const unsigned short* __restrict__ WfTl,
    const float* __restrict__ bfv,
    unsigned short* __restrict__ Mth,         // [12][64][64]
    unsigned short* __restrict__ Mtl)
{
  __shared__ float Al[64][64];
  __shared__ float Bl[64][64];
  int h = blockIdx.x, tid = threadIdx.x;

  for (int idx = tid; idx < 4096; idx += TPB) {
    int d = idx >> 6, i = idx & 63;
    int colr = h * 64 + d, colu = 768 + h * 64 + d;
    float wr = 0.f, wu = 0.f;
    if (i < 50) {
      wr = bf2f(WfTh[(size_t)colr * 64 + i]) + bf2f(WfTl[(size_t)colr * 64 + i]);
      wu = bf2f(WfTh[(size_t)colu * 64 + i]) + bf2f(WfTl[(size_t)colu * 64 + i]);
    } else if (i == 50) {
      wr = bfv[colr];
      wu = bfv[colu];
    }
    Al[d][i] = wr;
    Bl[d][i] = wu;
  }
  __syncthreads();
  for (int idx = tid; idx < 4096; idx += TPB) {
    int j = idx >> 6, i = idx & 63;
    float m = 0.f;
#pragma unroll 8
    for (int d = 0; d < 64; ++d) m += Al[d][i] * Bl[d][j];
    unsigned short hi = f2bf(m);
    size_t el = ((size_t)h * 64 + j) * 64 + i;
    Mth[el] = hi;
    Mtl[el] = f2bf(m - bf2f(hi));
  }
}

// ---------------------------------------------------------------------------
// MEGA: attention (bid<768, writes normalized Y) + wp rows [25600,61504)
// (bid>=768, 8 rows/block). Grid 5256 x 512.
// ---------------------------------------------------------------------------
__global__ __launch_bounds__(512) void attn_wp_y_k(
    const unsigned short* __restrict__ xh,    // [7688+][64] (homog col 50)
    const unsigned short* __restrict__ xl,
    const unsigned short* __restrict__ xT,    // [8][64][968]
    const unsigned short* __restrict__ Mth,   // [12][64][64]
    const unsigned short* __restrict__ Mtl,
    float* __restrict__ Y,                    // [96][961][64]
    const float* __restrict__ Wp1, const float* __restrict__ Wp2,
    float* __restrict__ wfold)
{
  __shared__ unsigned short sh[24576];       // 48 KB
  int bid = blockIdx.x;
  int tid = threadIdx.x;

  if (bid >= 768) {
    // ---------------- wp role: 8 waves, one wfold row each ----------------
    int u = bid - 768;
    int wv = tid >> 6, lane = tid & 63;
    float* w2 = (float*)sh;
    for (int i = tid; i < 1536; i += 512) w2[i] = Wp2[i];
    __syncthreads();
    int m = 25600 + u * 8 + wv;              // < 61504
    const float* row = Wp1 + (size_t)m * 1536;
    float s = 0.f;
#pragma unroll
    for (int k = 0; k < 6; ++k) {
      float4 a  = *(const float4*)(row + k * 256 + lane * 4);
      float4 ww = *(const float4*)&w2[k * 256 + lane * 4];
      s += a.x * ww.x + a.y * ww.y + a.z * ww.z + a.w * ww.w;
    }
#pragma unroll
    for (int off = 32; off >= 1; off >>= 1) s += __shfl_xor(s, off, 64);
    if (lane == 0) wfold[m] = s;
    return;
  }

  // ---------------- attention role ----------------
  int qb = bid & 7, hb = bid >> 3;
  int h = hb >> 3, b = hb & 7;
  int n0 = qb * 128;
  int w = tid >> 6, lane = tid & 63;
  int g = lane >> 4, c = lane & 15;
  int xb = b * 961;
  unsigned short* Kbuf[2] = {sh, sh + 4096};
  unsigned short* Vbuf[2] = {sh + 8192, sh + 12288};
  unsigned short* pw = sh + 16384 + w * 1024;

  int srow = tid >> 3, ss = tid & 7;
  int sel = srow * 64 + 8 * (ss ^ (srow & 7));
  const unsigned short* ksrc = xh + (size_t)xb * 64 + ss * 8;
  const unsigned short* vsrc = xT + ((size_t)b * 64 + srow) * 968 + ss * 8;
  int4 kv0 = *(const int4*)(ksrc + (size_t)srow * 64);
  int4 vv0 = *(const int4*)(vsrc);

  // ---- Z = x~_q @ M~_h (split precision) ----
  int qrow = n0 + w * 16 + c;
  if (qrow > 960) qrow = 960;
  size_t rowb = (size_t)(xb + qrow) * 64;
  bf16x8 axh0 = *(const bf16x8*)&xh[rowb + g * 8];
  bf16x8 axh1 = *(const bf16x8*)&xh[rowb + 32 + g * 8];
  bf16x8 axl0 = *(const bf16x8*)&xl[rowb + g * 8];
  bf16x8 axl1 = *(const bf16x8*)&xl[rowb + 32 + g * 8];

  f32x4 zero4 = {0.f, 0.f, 0.f, 0.f};
  f32x4 zacc[4] = {zero4, zero4, zero4, zero4};
#pragma unroll
  for (int ct = 0; ct < 4; ++ct) {
    int j = c * 4 + ct;
    size_t mb = ((size_t)h * 64 + j) * 64;
    bf16x8 bh0 = *(const bf16x8*)&Mth[mb + g * 8];
    bf16x8 bh1 = *(const bf16x8*)&Mth[mb + 32 + g * 8];
    bf16x8 bl0 = *(const bf16x8*)&Mtl[mb + g * 8];
    bf16x8 bl1 = *(const bf16x8*)&Mtl[mb + 32 + g * 8];
    zacc[ct] = MFMA16(axh0, bh0, zacc[ct]);
    zacc[ct] = MFMA16(axh1, bh1, zacc[ct]);
    zacc[ct] = MFMA16(axl0, bh0, zacc[ct]);
    zacc[ct] = MFMA16(axl1, bh1, zacc[ct]);
    zacc[ct] = MFMA16(axh0, bl0, zacc[ct]);
    zacc[ct] = MFMA16(axh1, bl1, zacc[ct]);
  }
#pragma unroll
  for (int r = 0; r < 4; ++r) {
    unsigned short pb[4];
#pragma unroll
    for (int ct = 0; ct < 4; ++ct) pb[ct] = f2bf(zacc[ct][r]);
    int q = g * 4 + r;
    int e0 = (c * 4) ^ ((q & 7) * 8);
    *(unsigned int*)&pw[q * 64 + e0] =
        (unsigned int)pb[0] | ((unsigned int)pb[1] << 16);
    *(unsigned int*)&pw[q * 64 + e0 + 2] =
        (unsigned int)pb[2] | ((unsigned int)pb[3] << 16);
  }
  bf16x8 zf0 = *(const bf16x8*)&pw[c * 64 + ((g * 8) ^ ((c & 7) * 8))];
  bf16x8 zf1 = *(const bf16x8*)&pw[c * 64 + ((32 + g * 8) ^ ((c & 7) * 8))];

  bf16x8 ones;
#pragma unroll
  for (int i = 0; i < 8; ++i) ones[i] = (short)0x3F80;  // bf16 1.0

  *(int4*)&Kbuf[0][sel] = kv0;
  *(int4*)&Vbuf[0][sel] = vv0;
  __syncthreads();

  f32x4 pxacc[4] = {zero4, zero4, zero4, zero4};
  f32x4 rowacc = zero4;

  unsigned short* Kc = Kbuf[0];
  unsigned short* Vc = Vbuf[0];
  unsigned short* Kn = Kbuf[1];
  unsigned short* Vn = Vbuf[1];

  for (int kt = 0; kt < 16; ++kt) {
    int4 pk, pv;
    bool pre = (kt < 15);
    if (pre) {
      int keyg = (kt + 1) * 64 + srow;
      int kcl = keyg > 960 ? 960 : keyg;
      pk = *(const int4*)(ksrc + (size_t)kcl * 64);
      pv = *(const int4*)(vsrc + (kt + 1) * 64);
    }

    f32x4 sa[4] = {zero4, zero4, zero4, zero4};
    __builtin_amdgcn_s_setprio(1);
#pragma unroll
    for (int ct = 0; ct < 4; ++ct) {
      int key = c * 4 + ct;
      int sw = (key & 7) * 8;
      bf16x8 k0 = *(const bf16x8*)&Kc[key * 64 + ((g * 8) ^ sw)];
      bf16x8 k1 = *(const bf16x8*)&Kc[key * 64 + ((32 + g * 8) ^ sw)];
      sa[ct] = MFMA16(zf0, k0, sa[ct]);
      sa[ct] = MFMA16(zf1, k1, sa[ct]);
    }
    __builtin_amdgcn_s_setprio(0);

    if (kt < 15) {
#pragma unroll
      for (int r = 0; r < 4; ++r) {
        unsigned short pb[4];
#pragma unroll
        for (int ct = 0; ct < 4; ++ct)
          pb[ct] = f2bf(__expf(sa[ct][r]));
        int q = g * 4 + r;
        int e0 = (c * 4) ^ ((q & 7) * 8);
        *(unsigned int*)&pw[q * 64 + e0] =
            (unsigned int)pb[0] | ((unsigned int)pb[1] << 16);
        *(unsigned int*)&pw[q * 64 + e0 + 2] =
            (unsigned int)pb[2] | ((unsigned int)pb[3] << 16);
      }
    } else {
#pragma unroll
      for (int r = 0; r < 4; ++r) {
        unsigned short pb[4];
#pragma unroll
        for (int ct = 0; ct < 4; ++ct) {
          int keyg = kt * 64 + c * 4 + ct;
          pb[ct] = (keyg <= 960) ? f2bf(__expf(sa[ct][r])) : (unsigned short)0;
        }
        int q = g * 4 + r;
        int e0 = (c * 4) ^ ((q & 7) * 8);
        *(unsigned int*)&pw[q * 64 + e0] =
            (unsigned int)pb[0] | ((unsigned int)pb[1] << 16);
        *(unsigned int*)&pw[q * 64 + e0 + 2] =
            (unsigned int)pb[2] | ((unsigned int)pb[3] << 16);
      }
    }

    if (pre) {
      *(int4*)&Kn[sel] = pk;
      *(int4*)&Vn[sel] = pv;
    }

    __builtin_amdgcn_s_setprio(1);
#pragma unroll
    for (int kk = 0; kk < 2; ++kk) {
      bf16x8 pa = *(const bf16x8*)&pw[c * 64 + ((kk * 32 + g * 8) ^ ((c & 7) * 8))];
      rowacc = MFMA16(pa, ones, rowacc);
#pragma unroll
      for (int dt = 0; dt < 4; ++dt) {
        int d = dt * 16 + c;
        bf16x8 vf = *(const bf16x8*)&Vc[d * 64 + ((kk * 32 + g * 8) ^ ((d & 7) * 8))];
        pxacc[dt] = MFMA16(pa, vf, pxacc[dt]);
      }
    }
    __builtin_amdgcn_s_setprio(0);

    __syncthreads();
    unsigned short* t;
    t = Kc; Kc = Kn; Kn = t;
    t = Vc; Vc = Vn; Vn = t;
  }

  // ---- epilogue: write normalized context Y ----
  int nbase = n0 + w * 16 + g * 4;
  float* yb = Y + (size_t)hb * 961 * 64;
#pragma unroll
  for (int r = 0; r < 4; ++r) {
    int n = nbase + r;
    if (n > 960) continue;
    float inv = 1.f / rowacc[r];
#pragma unroll
    for (int dt = 0; dt < 4; ++dt)
      yb[(size_t)n * 64 + dt * 16 + c] = pxacc[dt][r] * inv;
  }
}

// ---------------------------------------------------------------------------
// final_k: per (h,b): T[f][d] = sum_n Y[n][f]*wfold[n][d] (LDS tiled), then
// out[b*12+h] += sum_{f,d} T[f][d]*Wv_aug[f][d]. Grid 96 x 256.
// ---------------------------------------------------------------------------
__global__ __launch_bounds__(TPB) void final_k(
    const float* __restrict__ Y,              // [96][961][64]
    const float* __restrict__ wfold,          // [961][64]
    const unsigned short* __restrict__ WfTh,
    const unsigned short* __restrict__ WfTl,
    const float* __restrict__ bfv,
    float* __restrict__ out)
{
  __shared__ float yl[64][64];
  __shared__ float wl[64][64];
  __shared__ float red[4];
  int hb = blockIdx.x;
  int h = hb >> 3, b = hb & 7;
  int tid = threadIdx.x;
  int f = tid >> 2, d16 = (tid & 3) * 16;
  float T[16] = {};
  const float* ybase = Y + (size_t)hb * 961 * 64;

  for (int t0 = 0; t0 < 961; t0 += 64) {
    int rows = 961 - t0 < 64 ? 961 - t0 : 64;
    for (int idx = tid; idx < 4096; idx += TPB) {
      int nl = idx >> 6, dd = idx & 63;
      float yv = 0.f, wv = 0.f;
      if (nl < rows) {
        yv = ybase[(size_t)(t0 + nl) * 64 + dd];
        wv = wfold[(size_t)(t0 + nl) * 64 + dd];
      }
      yl[nl][dd] = yv;
      wl[nl][dd] = wv;
    }
    __syncthreads();
    for (int nl = 0; nl < 64; ++nl) {
      float yv = yl[nl][f];
      float4 w0 = *(const float4*)&wl[nl][d16];
      float4 w1 = *(const float4*)&wl[nl][d16 + 4];
      float4 w2 = *(const float4*)&wl[nl][d16 + 8];
      float4 w3 = *(const float4*)&wl[nl][d16 + 12];
      T[0] = fmaf(yv, w0.x, T[0]);   T[1] = fmaf(yv, w0.y, T[1]);
      T[2] = fmaf(yv, w0.z, T[2]);   T[3] = fmaf(yv, w0.w, T[3]);
      T[4] = fmaf(yv, w1.x, T[4]);   T[5] = fmaf(yv, w1.y, T[5]);
      T[6] = fmaf(yv, w1.z, T[6]);   T[7] = fmaf(yv, w1.w, T[7]);
      T[8] = fmaf(yv, w2.x, T[8]);   T[9] = fmaf(yv, w2.y, T[9]);
      T[10] = fmaf(yv, w2.z, T[10]); T[11] = fmaf(yv, w2.w, T[11]);
      T[12] = fmaf(yv, w3.x, T[12]); T[13] = fmaf(yv, w3.y, T[13]);
      T[14] = fmaf(yv, w3.z, T[14]); T[15] = fmaf(yv, w3.w, T[15]);
    }
    __syncthreads();
  }

  float s = 0.f;
  if (f <= 50) {
#pragma unroll
    for (int j = 0; j < 16; ++j) {
      int d = d16 + j;
      int colv = 1536 + h * 64 + d;
      float wv;
      if (f == 50) wv = bfv[colv];
      else wv = bf2f(WfTh[(size_t)colv * 64 + f]) + bf2f(WfTl[(size_t)colv * 64 + f]);
      s = fmaf(T[j], wv, s);
    }
  }
  int lane = tid & 63, wvv = tid >> 6;
#pragma unroll
  for (int off = 32; off >= 1; off >>= 1) s += __shfl_xor(s, off, 64);
  if (lane == 0) red[wvv] = s;
  __syncthreads();
  if (tid == 0) out[b * 12 + h] += red[0] + red[1] + red[2] + red[3];
}

// ---------------------------------------------------------------------------
extern "C" void kernel_launch(void* const* d_in, const int* in_sizes, int n_in,
                              void* d_out, int out_size, void* d_ws, size_t ws_size,
                              hipStream_t stream)
{
  const float* x    = (const float*)d_in[0];
  const float* W1   = (const float*)d_in[1];
  const float* b1   = (const float*)d_in[2];
  const float* W2   = (const float*)d_in[3];
  const float* b2   = (const float*)d_in[4];
  const float* W3   = (const float*)d_in[5];
  const float* b3   = (const float*)d_in[6];
  const float* W4   = (const float*)d_in[7];
  const float* b4   = (const float*)d_in[8];
  const float* Wruv = (const float*)d_in[9];
  const float* bruv = (const float*)d_in[10];
  const float* Wp1  = (const float*)d_in[11];
  const float* bp1  = (const float*)d_in[12];
  const float* Wp2  = (const float*)d_in[13];
  const float* bp2  = (const float*)d_in[14];
  float* out = (float*)d_out;

  char* base = (char*)d_ws;
  size_t off = 0;
  auto alloc = [&](size_t bytes) -> void* {
    void* p = base + off;
    off = (off + bytes + 255) & ~(size_t)255;
    return p;
  };
  float* aug1  = (float*)alloc(51 * 200 * 4);
  float* aug2  = (float*)alloc(51 * 200 * 4);
  float* aug3  = (float*)alloc(51 * 768 * 4);
  unsigned short* WfTh = (unsigned short*)alloc((size_t)2304 * 64 * 2);
  unsigned short* WfTl = (unsigned short*)alloc((size_t)2304 * 64 * 2);
  unsigned short* xh   = (unsigned short*)alloc((size_t)(7688 + 64) * 64 * 2);
  unsigned short* xl   = (unsigned short*)alloc((size_t)(7688 + 64) * 64 * 2);
  unsigned short* xT   = (unsigned short*)alloc((size_t)8 * 64 * 968 * 2 + 1024);
  unsigned short* Mth  = (unsigned short*)alloc((size_t)12 * 64 * 64 * 2);
  unsigned short* Mtl  = (unsigned short*)alloc((size_t)12 * 64 * 64 * 2);
  float* Yb    = (float*)alloc((size_t)96 * 961 * 64 * 4);   // 23.6 MB
  float* bfv   = (float*)alloc(2304 * 4);
  float* wfold = (float*)alloc(61504 * 4);
  if (off > ws_size) return;

  dim3 tb(TPB);

  // ---- fold chain stages 1-3, each with a small wp slice (1600 units) ----
  fold_wp_fused_k<<<dim3(4 + 1600 + 1), tb, 0, stream>>>(
      W1, b1, W2, b2, aug1, 200, 200, 4,
      Wp1, Wp2, wfold, 0, 1600, bp1, bp2, out);
  fold_wp_fused_k<<<dim3(4 + 1600), tb, 0, stream>>>(
      aug1, aug1 + 50 * 200, W3, b3, aug2, 200, 200, 4,
      Wp1, Wp2, wfold, 1600, 1600, bp1, bp2, out);
  fold_wp_fused_k<<<dim3(12 + 1600), tb, 0, stream>>>(
      aug2, aug2 + 50 * 200, W4, b4, aug3, 200, 768, 12,
      Wp1, Wp2, wfold, 3200, 1600, bp1, bp2, out);

  // ---- stage4 + x-prep + wp slice (units 4800..6400 -> rows < 25600) ----
  fold4_fused_k<<<dim3(157 + 1600), tb, 0, stream>>>(
      aug3, Wruv, bruv, WfTh, WfTl, bfv, x, xh, xl, xT,
      Wp1, Wp2, wfold, 4800, 1600);

  // ---- M~ precompute ----
  prepM_k<<<dim3(12), tb, 0, stream>>>(WfTh, WfTl, bfv, Mth, Mtl);

  // ---- MEGA: attention (-> Y) overlapped with wp rows [25600, 61504) ----
  attn_wp_y_k<<<dim3(768 + 4488), dim3(512), 0, stream>>>(
      xh, xl, xT, Mth, Mtl, Yb, Wp1, Wp2, wfold);

  // ---- final: T = Y^T @ wfold per (h,b), dot with Wv_aug ----
  final_k<<<dim3(96), tb, 0, stream>>>(Yb, wfold, WfTh, WfTl, bfv, out);
}

// Round 23
// 316.934 us; speedup vs baseline: 1.4294x; 1.4294x over previous
//
#include <hip/hip_runtime.h>
#include <hip/hip_bf16.h>

#define TPB 256

typedef __attribute__((ext_vector_type(8))) short bf16x8;
typedef __attribute__((ext_vector_type(4))) float f32x4;

static __device__ __forceinline__ unsigned short f2bf(float f) {
  union { float f; unsigned int u; } x; x.f = f;
  unsigned int r = x.u + 0x7FFF + ((x.u >> 16) & 1);   // RNE
  return (unsigned short)(r >> 16);
}
static __device__ __forceinline__ float bf2f(unsigned short h) {
  union { unsigned int u; float f; } x; x.u = ((unsigned int)h) << 16;
  return x.f;
}

#define MFMA16(a, b, c) __builtin_amdgcn_mfma_f32_16x16x32_bf16(a, b, c, 0, 0, 0)

// ---------------------------------------------------------------------------
// Fused fold-stage kernel (stages 1-3) + wp slices + out-init.
// ---------------------------------------------------------------------------
__global__ __launch_bounds__(TPB) void fold_wp_fused_k(
    const float* __restrict__ A, const float* __restrict__ lastrow,
    const float* __restrict__ W, const float* __restrict__ bias,
    float* __restrict__ C, int K, int Nc, int gemmBlocks,
    const float* __restrict__ Wp1, const float* __restrict__ Wp2,
    float* __restrict__ wfold, int wpStart, int wpCount,
    const float* __restrict__ bp1, const float* __restrict__ bp2,
    float* __restrict__ out)
{
  __shared__ float As[64][68];
  __shared__ float Ws[64][68];
  __shared__ float red[4];
  int bid = blockIdx.x, tid = threadIdx.x;

  if (bid >= gemmBlocks) {
    int u = bid - gemmBlocks;
    int wv = tid >> 6, lane = tid & 63;
    if (u >= wpCount) {
      float s = 0.f;
      for (int i = tid; i < 1536; i += TPB) s += bp1[i] * Wp2[i];
#pragma unroll
      for (int off = 32; off >= 1; off >>= 1) s += __shfl_xor(s, off, 64);
      if (lane == 0) red[wv] = s;
      __syncthreads();
      if (tid < 96) out[tid] = red[0] + red[1] + red[2] + red[3] + bp2[0];
      return;
    }
    float* w2 = &As[0][0];
    for (int i = tid; i < 1536; i += TPB) w2[i] = Wp2[i];
    __syncthreads();
    int m = (wpStart + u) * 4 + wv;
    const float* row = Wp1 + (size_t)m * 1536;
    float s = 0.f;
#pragma unroll
    for (int k = 0; k < 6; ++k) {
      float4 a  = *(const float4*)(row + k * 256 + lane * 4);
      float4 ww = *(const float4*)&w2[k * 256 + lane * 4];
      s += a.x * ww.x + a.y * ww.y + a.z * ww.z + a.w * ww.w;
    }
#pragma unroll
    for (int off = 32; off >= 1; off >>= 1) s += __shfl_xor(s, off, 64);
    if (lane == 0) wfold[m] = s;
    return;
  }

  int col0 = bid * 64;
  int ty = tid >> 4, tx = tid & 15;
  float acc[4][4] = {};
  for (int k0 = 0; k0 < K; k0 += 64) {
#pragma unroll
    for (int i = 0; i < 16; ++i) {
      int idx = tid + i * TPB;
      int r = idx >> 6, kk = idx & 63;
      int gk = k0 + kk;
      float v = 0.f;
      if (gk < K) {
        if (r < 50) v = A[(size_t)r * K + gk];
        else if (r == 50) v = lastrow[gk];
      }
      As[kk][r] = v;
    }
#pragma unroll
    for (int i = 0; i < 16; ++i) {
      int idx = tid + i * TPB;
      int kk = idx >> 6, cc = idx & 63;
      int gk = k0 + kk, gc = col0 + cc;
      float v = 0.f;
      if (gk < K && gc < Nc) v = W[(size_t)gk * Nc + gc];
      Ws[kk][cc] = v;
    }
    __syncthreads();
#pragma unroll 8
    for (int kk = 0; kk < 64; ++kk) {
      float4 a4 = *(const float4*)&As[kk][ty * 4];
      float4 b4 = *(const float4*)&Ws[kk][tx * 4];
      float av[4] = {a4.x, a4.y, a4.z, a4.w};
      float bv[4] = {b4.x, b4.y, b4.z, b4.w};
#pragma unroll
      for (int i = 0; i < 4; ++i)
#pragma unroll
        for (int j = 0; j < 4; ++j)
          acc[i][j] = fmaf(av[i], bv[j], acc[i][j]);
    }
    __syncthreads();
  }
#pragma unroll
  for (int i = 0; i < 4; ++i) {
    int gr = ty * 4 + i;
    if (gr >= 51) continue;
#pragma unroll
    for (int j = 0; j < 4; ++j) {
      int gc = col0 + tx * 4 + j;
      if (gc >= Nc) continue;
      float v = acc[i][j];
      if (gr == 50) v += bias[gc];
      C[(size_t)gr * Nc + gc] = v;
    }
  }
}

// ---------------------------------------------------------------------------
// Fused stage4: gemm -> WfTh/WfTl/bfv; x-prep -> xh/xl/xT; wp slice.
// ---------------------------------------------------------------------------
__global__ __launch_bounds__(TPB) void fold4_fused_k(
    const float* __restrict__ aug3,
    const float* __restrict__ Wruv,
    const float* __restrict__ bruv,
    unsigned short* __restrict__ WfTh, unsigned short* __restrict__ WfTl,
    float* __restrict__ bfv,
    const float* __restrict__ x,
    unsigned short* __restrict__ xh, unsigned short* __restrict__ xl,
    unsigned short* __restrict__ xT,
    const float* __restrict__ Wp1, const float* __restrict__ Wp2,
    float* __restrict__ wfold, int wpStart, int wpCount)
{
  __shared__ float As[64][68];
  __shared__ float Ws[64][68];
  int bid = blockIdx.x, tid = threadIdx.x;

  if (bid >= 157) {
    int u = bid - 157;
    if (u >= wpCount) return;
    int wv = tid >> 6, lane = tid & 63;
    float* w2 = &As[0][0];
    for (int i = tid; i < 1536; i += TPB) w2[i] = Wp2[i];
    __syncthreads();
    int m = (wpStart + u) * 4 + wv;
    const float* row = Wp1 + (size_t)m * 1536;
    float s = 0.f;
#pragma unroll
    for (int k = 0; k < 6; ++k) {
      float4 a  = *(const float4*)(row + k * 256 + lane * 4);
      float4 ww = *(const float4*)&w2[k * 256 + lane * 4];
      s += a.x * ww.x + a.y * ww.y + a.z * ww.z + a.w * ww.w;
    }
#pragma unroll
    for (int off = 32; off >= 1; off >>= 1) s += __shfl_xor(s, off, 64);
    if (lane == 0) wfold[m] = s;
    return;
  }

  if (bid >= 36) {
    int row0 = (bid - 36) * 64;
#pragma unroll
    for (int i = 0; i < 16; ++i) {
      int idx = tid + i * TPB;
      int row = row0 + (idx >> 6), cc = idx & 63;
      if (row >= 7688) continue;
      float v = 0.f;
      if (cc < 50) v = x[(size_t)row * 50 + cc];
      else if (cc == 50) v = 1.0f;
      unsigned short hi = f2bf(v);
      xh[(size_t)row * 64 + cc] = hi;
      xl[(size_t)row * 64 + cc] = f2bf(v - bf2f(hi));
      int bb = row / 961;
      int nl = row - bb * 961;
      xT[((size_t)bb * 64 + cc) * 968 + nl] = hi;
    }
    return;
  }

  const int K = 768, Nc = 2304;
  const float* lastrow = aug3 + (size_t)50 * 768;
  int col0 = bid * 64;
  int ty = tid >> 4, tx = tid & 15;
  float acc[4][4] = {};
  for (int k0 = 0; k0 < K; k0 += 64) {
#pragma unroll
    for (int i = 0; i < 16; ++i) {
      int idx = tid + i * TPB;
      int r = idx >> 6, kk = idx & 63;
      int gk = k0 + kk;
      float v = 0.f;
      if (r < 50) v = aug3[(size_t)r * K + gk];
      else if (r == 50) v = lastrow[gk];
      As[kk][r] = v;
    }
#pragma unroll
    for (int i = 0; i < 16; ++i) {
      int idx = tid + i * TPB;
      int kk = idx >> 6, cc = idx & 63;
      Ws[kk][cc] = Wruv[(size_t)(k0 + kk) * Nc + col0 + cc];
    }
    __syncthreads();
#pragma unroll 8
    for (int kk = 0; kk < 64; ++kk) {
      float4 a4 = *(const float4*)&As[kk][ty * 4];
      float4 b4 = *(const float4*)&Ws[kk][tx * 4];
      float av[4] = {a4.x, a4.y, a4.z, a4.w};
      float bv[4] = {b4.x, b4.y, b4.z, b4.w};
#pragma unroll
      for (int i = 0; i < 4; ++i)
#pragma unroll
        for (int j = 0; j < 4; ++j)
          acc[i][j] = fmaf(av[i], bv[j], acc[i][j]);
    }
    __syncthreads();
  }
#pragma unroll
  for (int i = 0; i < 4; ++i) {
    int gr = ty * 4 + i;
    if (gr >= 51) continue;
#pragma unroll
    for (int j = 0; j < 4; ++j) {
      int gc = col0 + tx * 4 + j;
      float v = acc[i][j];
      if (gr == 50) {
        bfv[gc] = v + bruv[gc];
      } else {
        unsigned short hi = f2bf(v);
        size_t el = (size_t)gc * 64 + gr;
        WfTh[el] = hi;
        WfTl[el] = f2bf(v - bf2f(hi));
      }
    }
  }
}

// ---------------------------------------------------------------------------
// prep_k: M~T (unscaled; attention uses __expf) + wvf. r18-proven version.
// ---------------------------------------------------------------------------
__global__ __launch_bounds__(TPB) void prep_k(
    const unsigned short* __restrict__ WfTh,
    const unsigned short* __restrict__ WfTl,
    const float* __restrict__ bfv,
    const float* __restrict__ wfold,          // [961][64]
    unsigned short* __restrict__ Mth,         // [12][64][64]
    unsigned short* __restrict__ Mtl,
    float* __restrict__ wvf)                  // [12][961][64]
{
  __shared__ float Al[64][64];
  __shared__ float Bl[64][64];
  int bid = blockIdx.x, tid = threadIdx.x;

  if (bid < 12) {
    int h = bid;
    for (int idx = tid; idx < 4096; idx += TPB) {
      int d = idx >> 6, i = idx & 63;
      int colr = h * 64 + d, colu = 768 + h * 64 + d;
      float wr = 0.f, wu = 0.f;
      if (i < 50) {
        wr = bf2f(WfTh[(size_t)colr * 64 + i]) + bf2f(WfTl[(size_t)colr * 64 + i]);
        wu = bf2f(WfTh[(size_t)colu * 64 + i]) + bf2f(WfTl[(size_t)colu * 64 + i]);
      } else if (i == 50) {
        wr = bfv[colr];
        wu = bfv[colu];
      }
      Al[d][i] = wr;
      Bl[d][i] = wu;
    }
    __syncthreads();
    for (int idx = tid; idx < 4096; idx += TPB) {
      int j = idx >> 6, i = idx & 63;
      float m = 0.f;
#pragma unroll 8
      for (int d = 0; d < 64; ++d) m += Al[d][i] * Bl[d][j];
      unsigned short hi = f2bf(m);
      size_t el = ((size_t)h * 64 + j) * 64 + i;
      Mth[el] = hi;
      Mtl[el] = f2bf(m - bf2f(hi));
    }
    return;
  }

  int u = bid - 12;
  int h = u >> 4, nb = u & 15;
  for (int idx = tid; idx < 4096; idx += TPB) {
    int d = idx >> 6, f = idx & 63;
    int colv = 1536 + h * 64 + d;
    float wv = 0.f;
    if (f < 50)
      wv = bf2f(WfTh[(size_t)colv * 64 + f]) + bf2f(WfTl[(size_t)colv * 64 + f]);
    else if (f == 50)
      wv = bfv[colv];
    Al[d][f] = wv;
    int nl = idx >> 6, dd = idx & 63;
    int n = nb * 64 + nl;
    Bl[nl][dd] = (n <= 960) ? wfold[(size_t)n * 64 + dd] : 0.f;
  }
  __syncthreads();
  for (int idx = tid; idx < 4096; idx += TPB) {
    int nl = idx >> 6, f = idx & 63;
    int n = nb * 64 + nl;
    if (n > 960) continue;
    float s = 0.f;
#pragma unroll 8
    for (int d = 0; d < 64; ++d) s += Bl[nl][d] * Al[d][f];
    wvf[((size_t)h * 961 + n) * 64 + f] = s;
  }
}

// ---------------------------------------------------------------------------
// x-based MFMA flash attention with fused final projection (r18/r21-proven:
// __expf + f2bf RNE pack). Grid 768 x 512.
// ---------------------------------------------------------------------------
__global__ __launch_bounds__(512) void attn_x_k(
    const unsigned short* __restrict__ xh,    // [7688+][64] (homog col 50)
    const unsigned short* __restrict__ xl,
    const unsigned short* __restrict__ xT,    // [8][64][968]
    const unsigned short* __restrict__ Mth,   // [12][64][64]
    const unsigned short* __restrict__ Mtl,
    const float* __restrict__ wvf,            // [12][961][64]
    float* __restrict__ out)
{
  __shared__ unsigned short sh[24576];       // 48 KB
  int bid = blockIdx.x;
  int tid = threadIdx.x;

  int qb = bid & 7, hb = bid >> 3;
  int h = hb >> 3, b = hb & 7;
  int n0 = qb * 128;
  int w = tid >> 6, lane = tid & 63;
  int g = lane >> 4, c = lane & 15;
  int xb = b * 961;
  unsigned short* Kbuf[2] = {sh, sh + 4096};
  unsigned short* Vbuf[2] = {sh + 8192, sh + 12288};
  unsigned short* pw = sh + 16384 + w * 1024;

  int srow = tid >> 3, ss = tid & 7;
  int sel = srow * 64 + 8 * (ss ^ (srow & 7));
  const unsigned short* ksrc = xh + (size_t)xb * 64 + ss * 8;
  const unsigned short* vsrc = xT + ((size_t)b * 64 + srow) * 968 + ss * 8;
  int4 kv0 = *(const int4*)(ksrc + (size_t)srow * 64);
  int4 vv0 = *(const int4*)(vsrc);

  // ---- Z = x~_q @ M~_h (split precision) ----
  int qrow = n0 + w * 16 + c;
  if (qrow > 960) qrow = 960;
  size_t rowb = (size_t)(xb + qrow) * 64;
  bf16x8 axh0 = *(const bf16x8*)&xh[rowb + g * 8];
  bf16x8 axh1 = *(const bf16x8*)&xh[rowb + 32 + g * 8];
  bf16x8 axl0 = *(const bf16x8*)&xl[rowb + g * 8];
  bf16x8 axl1 = *(const bf16x8*)&xl[rowb + 32 + g * 8];

  f32x4 zero4 = {0.f, 0.f, 0.f, 0.f};
  f32x4 zacc[4] = {zero4, zero4, zero4, zero4};
#pragma unroll
  for (int ct = 0; ct < 4; ++ct) {
    int j = c * 4 + ct;
    size_t mb = ((size_t)h * 64 + j) * 64;
    bf16x8 bh0 = *(const bf16x8*)&Mth[mb + g * 8];
    bf16x8 bh1 = *(const bf16x8*)&Mth[mb + 32 + g * 8];
    bf16x8 bl0 = *(const bf16x8*)&Mtl[mb + g * 8];
    bf16x8 bl1 = *(const bf16x8*)&Mtl[mb + 32 + g * 8];
    zacc[ct] = MFMA16(axh0, bh0, zacc[ct]);
    zacc[ct] = MFMA16(axh1, bh1, zacc[ct]);
    zacc[ct] = MFMA16(axl0, bh0, zacc[ct]);
    zacc[ct] = MFMA16(axl1, bh1, zacc[ct]);
    zacc[ct] = MFMA16(axh0, bl0, zacc[ct]);
    zacc[ct] = MFMA16(axh1, bl1, zacc[ct]);
  }
#pragma unroll
  for (int r = 0; r < 4; ++r) {
    unsigned short pb[4];
#pragma unroll
    for (int ct = 0; ct < 4; ++ct) pb[ct] = f2bf(zacc[ct][r]);
    int q = g * 4 + r;
    int e0 = (c * 4) ^ ((q & 7) * 8);
    *(unsigned int*)&pw[q * 64 + e0] =
        (unsigned int)pb[0] | ((unsigned int)pb[1] << 16);
    *(unsigned int*)&pw[q * 64 + e0 + 2] =
        (unsigned int)pb[2] | ((unsigned int)pb[3] << 16);
  }
  bf16x8 zf0 = *(const bf16x8*)&pw[c * 64 + ((g * 8) ^ ((c & 7) * 8))];
  bf16x8 zf1 = *(const bf16x8*)&pw[c * 64 + ((32 + g * 8) ^ ((c & 7) * 8))];

  bf16x8 ones;
#pragma unroll
  for (int i = 0; i < 8; ++i) ones[i] = (short)0x3F80;  // bf16 1.0

  *(int4*)&Kbuf[0][sel] = kv0;
  *(int4*)&Vbuf[0][sel] = vv0;
  __syncthreads();

  f32x4 pxacc[4] = {zero4, zero4, zero4, zero4};
  f32x4 rowacc = zero4;

  unsigned short* Kc = Kbuf[0];
  unsigned short* Vc = Vbuf[0];
  unsigned short* Kn = Kbuf[1];
  unsigned short* Vn = Vbuf[1];

  for (int kt = 0; kt < 16; ++kt) {
    int4 pk, pv;
    bool pre = (kt < 15);
    if (pre) {
      int keyg = (kt + 1) * 64 + srow;
      int kcl = keyg > 960 ? 960 : keyg;
      pk = *(const int4*)(ksrc + (size_t)kcl * 64);
      pv = *(const int4*)(vsrc + (kt + 1) * 64);
    }

    f32x4 sa[4] = {zero4, zero4, zero4, zero4};
    __builtin_amdgcn_s_setprio(1);
#pragma unroll
    for (int ct = 0; ct < 4; ++ct) {
      int key = c * 4 + ct;
      int sw = (key & 7) * 8;
      bf16x8 k0 = *(const bf16x8*)&Kc[key * 64 + ((g * 8) ^ sw)];
      bf16x8 k1 = *(const bf16x8*)&Kc[key * 64 + ((32 + g * 8) ^ sw)];
      sa[ct] = MFMA16(zf0, k0, sa[ct]);
      sa[ct] = MFMA16(zf1, k1, sa[ct]);
    }
    __builtin_amdgcn_s_setprio(0);

    if (kt < 15) {
#pragma unroll
      for (int r = 0; r < 4; ++r) {
        unsigned short pb[4];
#pragma unroll
        for (int ct = 0; ct < 4; ++ct)
          pb[ct] = f2bf(__expf(sa[ct][r]));
        int q = g * 4 + r;
        int e0 = (c * 4) ^ ((q & 7) * 8);
        *(unsigned int*)&pw[q * 64 + e0] =
            (unsigned int)pb[0] | ((unsigned int)pb[1] << 16);
        *(unsigned int*)&pw[q * 64 + e0 + 2] =
            (unsigned int)pb[2] | ((unsigned int)pb[3] << 16);
      }
    } else {
#pragma unroll
      for (int r = 0; r < 4; ++r) {
        unsigned short pb[4];
#pragma unroll
        for (int ct = 0; ct < 4; ++ct) {
          int keyg = kt * 64 + c * 4 + ct;
          pb[ct] = (keyg <= 960) ? f2bf(__expf(sa[ct][r])) : (unsigned short)0;
        }
        int q = g * 4 + r;
        int e0 = (c * 4) ^ ((q & 7) * 8);
        *(unsigned int*)&pw[q * 64 + e0] =
            (unsigned int)pb[0] | ((unsigned int)pb[1] << 16);
        *(unsigned int*)&pw[q * 64 + e0 + 2] =
            (unsigned int)pb[2] | ((unsigned int)pb[3] << 16);
      }
    }

    if (pre) {
      *(int4*)&Kn[sel] = pk;
      *(int4*)&Vn[sel] = pv;
    }

    __builtin_amdgcn_s_setprio(1);
#pragma unroll
    for (int kk = 0; kk < 2; ++kk) {
      bf16x8 pa = *(const bf16x8*)&pw[c * 64 + ((kk * 32 + g * 8) ^ ((c & 7) * 8))];
      rowacc = MFMA16(pa, ones, rowacc);
#pragma unroll
      for (int dt = 0; dt < 4; ++dt) {
        int d = dt * 16 + c;
        bf16x8 vf = *(const bf16x8*)&Vc[d * 64 + ((kk * 32 + g * 8) ^ ((d & 7) * 8))];
        pxacc[dt] = MFMA16(pa, vf, pxacc[dt]);
      }
    }
    __builtin_amdgcn_s_setprio(0);

    __syncthreads();
    unsigned short* t;
    t = Kc; Kc = Kn; Kn = t;
    t = Vc; Vc = Vn; Vn = t;
  }

  // ---- fused final: part = sum of PX~ . wvf_h / rowsum ----
  int nbase = n0 + w * 16 + g * 4;
  float part = 0.f;
#pragma unroll
  for (int r = 0; r < 4; ++r) {
    int n = nbase + r;
    if (n > 960) continue;
    float inv = 1.f / rowacc[r];
    const float* wv = wvf + ((size_t)h * 961 + n) * 64;
#pragma unroll
    for (int dt = 0; dt < 4; ++dt)
      part += pxacc[dt][r] * inv * wv[dt * 16 + c];
  }
#pragma unroll
  for (int off = 32; off >= 1; off >>= 1) part += __shfl_xor(part, off, 64);
  float* red = (float*)sh;
  if (lane == 0) red[w] = part;
  __syncthreads();
  if (tid == 0) {
    float tot = red[0] + red[1] + red[2] + red[3] +
                red[4] + red[5] + red[6] + red[7];
    atomicAdd(&out[b * 12 + h], tot);
  }
}

// ---------------------------------------------------------------------------
extern "C" void kernel_launch(void* const* d_in, const int* in_sizes, int n_in,
                              void* d_out, int out_size, void* d_ws, size_t ws_size,
                              hipStream_t stream)
{
  const float* x    = (const float*)d_in[0];
  const float* W1   = (const float*)d_in[1];
  const float* b1   = (const float*)d_in[2];
  const float* W2   = (const float*)d_in[3];
  const float* b2   = (const float*)d_in[4];
  const float* W3   = (const float*)d_in[5];
  const float* b3   = (const float*)d_in[6];
  const float* W4   = (const float*)d_in[7];
  const float* b4   = (const float*)d_in[8];
  const float* Wruv = (const float*)d_in[9];
  const float* bruv = (const float*)d_in[10];
  const float* Wp1  = (const float*)d_in[11];
  const float* bp1  = (const float*)d_in[12];
  const float* Wp2  = (const float*)d_in[13];
  const float* bp2  = (const float*)d_in[14];
  float* out = (float*)d_out;

  char* base = (char*)d_ws;
  size_t off = 0;
  auto alloc = [&](size_t bytes) -> void* {
    void* p = base + off;
    off = (off + bytes + 255) & ~(size_t)255;
    return p;
  };
  float* aug1  = (float*)alloc(51 * 200 * 4);
  float* aug2  = (float*)alloc(51 * 200 * 4);
  float* aug3  = (float*)alloc(51 * 768 * 4);
  unsigned short* WfTh = (unsigned short*)alloc((size_t)2304 * 64 * 2);
  unsigned short* WfTl = (unsigned short*)alloc((size_t)2304 * 64 * 2);
  unsigned short* xh   = (unsigned short*)alloc((size_t)(7688 + 64) * 64 * 2);
  unsigned short* xl   = (unsigned short*)alloc((size_t)(7688 + 64) * 64 * 2);
  unsigned short* xT   = (unsigned short*)alloc((size_t)8 * 64 * 968 * 2 + 1024);
  unsigned short* Mth  = (unsigned short*)alloc((size_t)12 * 64 * 64 * 2);
  unsigned short* Mtl  = (unsigned short*)alloc((size_t)12 * 64 * 64 * 2);
  float* wvf   = (float*)alloc((size_t)12 * 961 * 64 * 4);
  float* bfv   = (float*)alloc(2304 * 4);
  float* wfold = (float*)alloc(61504 * 4);
  if (off > ws_size) return;

  dim3 tb(TPB);

  // ---- fold chain stages 1-3, each fused with a BALANCED wp slice (3844) ----
  fold_wp_fused_k<<<dim3(4 + 3844 + 1), tb, 0, stream>>>(
      W1, b1, W2, b2, aug1, 200, 200, 4,
      Wp1, Wp2, wfold, 0, 3844, bp1, bp2, out);
  fold_wp_fused_k<<<dim3(4 + 3844), tb, 0, stream>>>(
      aug1, aug1 + 50 * 200, W3, b3, aug2, 200, 200, 4,
      Wp1, Wp2, wfold, 3844, 3844, bp1, bp2, out);
  fold_wp_fused_k<<<dim3(12 + 3844), tb, 0, stream>>>(
      aug2, aug2 + 50 * 200, W4, b4, aug3, 200, 768, 12,
      Wp1, Wp2, wfold, 7688, 3844, bp1, bp2, out);

  // ---- stage4 + x-prep (xh/xl/xT) + last wp slice (3844) ----
  fold4_fused_k<<<dim3(157 + 3844), tb, 0, stream>>>(
      aug3, Wruv, bruv, WfTh, WfTl, bfv, x, xh, xl, xT,
      Wp1, Wp2, wfold, 11532, 3844);

  // ---- M~ + wvf precompute ----
  prep_k<<<dim3(204), tb, 0, stream>>>(WfTh, WfTl, bfv, wfold, Mth, Mtl, wvf);

  // ---- x-based attention with fused final projection ----
  attn_x_k<<<dim3(768), dim3(512), 0, stream>>>(xh, xl, xT, Mth, Mtl, wvf, out);
}